// Round 9
// baseline (264.923 us; speedup 1.0000x reference)
//
#include <hip/hip_runtime.h>
#include <hip/hip_bf16.h>

typedef __attribute__((ext_vector_type(8))) short          s16x8;
typedef __attribute__((ext_vector_type(8))) unsigned short u16x8;
typedef __attribute__((ext_vector_type(4))) float          f4;
typedef __attribute__((ext_vector_type(2))) float          f2;
typedef __attribute__((ext_vector_type(4))) unsigned int   u32x4;
typedef __attribute__((ext_vector_type(2))) unsigned int   u32x2;

#define NPIX 32768   // 2*128*128 pixels (b folded in)

__device__ __forceinline__ float bf2f(unsigned short u) {
    union { unsigned int i; float f; } x; x.i = ((unsigned int)u) << 16; return x.f;
}
__device__ __forceinline__ float blo(unsigned int w) {
    union { unsigned int i; float f; } x; x.i = w << 16; return x.f;
}
__device__ __forceinline__ float bhi(unsigned int w) {
    union { unsigned int i; float f; } x; x.i = w & 0xffff0000u; return x.f;
}
__device__ __forceinline__ unsigned short f2bf(float f) {
    __hip_bfloat16 h = __float2bfloat16(f);
    return *reinterpret_cast<unsigned short*>(&h);
}
__device__ __forceinline__ unsigned int pk2(float a, float b) {
    return (unsigned int)f2bf(a) | ((unsigned int)f2bf(b) << 16);
}
__device__ __forceinline__ void gload_lds16(const void* g, void* l) {
    __builtin_amdgcn_global_load_lds(
        (const __attribute__((address_space(1))) unsigned int*)g,
        (__attribute__((address_space(3))) unsigned int*)l, 16, 0, 0);
}

// Convert the 4 weight matrices (each 512x512 fp32) to bf16, concatenated.
__global__ __launch_bounds__(256) void cvt_w4(const float* __restrict__ a,
                                              const float* __restrict__ b,
                                              const float* __restrict__ c,
                                              const float* __restrict__ d,
                                              unsigned short* __restrict__ o) {
    const int i   = (blockIdx.x * 256 + threadIdx.x) * 8;
    const int seg = i >> 18;
    const int off = i & 262143;
    const float* s = (seg == 0) ? a : (seg == 1) ? b : (seg == 2) ? c : d;
    f4 x0 = *(const f4*)(s + off);
    f4 x1 = *(const f4*)(s + off + 4);
    unsigned short t[8];
    t[0] = f2bf(x0[0]); t[1] = f2bf(x0[1]); t[2] = f2bf(x0[2]); t[3] = f2bf(x0[3]);
    t[4] = f2bf(x1[0]); t[5] = f2bf(x1[1]); t[6] = f2bf(x1[2]); t[7] = f2bf(x1[3]);
    *(u16x8*)(o + i) = *(u16x8*)t;
}

// Projection GEMM: OUT[h][pix][d] (bf16, head-major) =
//   (sum_k A[pix][k] * W[c][k] + bias[c]) * scale,  c = h*32+d.
// A panel (64 pix x 512 k fp32 = 128 KB) loaded as ONE CONTIGUOUS stream
// (DRAM-sequential, the R8 diagnosis), cvt'd to bf16 in padded LDS.
// W: gload_lds double-buffer, counted vmcnt. Swapped MFMA roles: D col=pixel,
// rows=channels -> each lane holds 4 consecutive d -> b64 packed stores.
__global__ __launch_bounds__(256) void gemm_proj(const float* __restrict__ Af,
                                                 const unsigned short* __restrict__ Wb,
                                                 const float* __restrict__ bias,
                                                 unsigned short* __restrict__ Out,
                                                 float scale) {
    constexpr int AP = 1040;            // bytes per padded LDS row (520 shorts)
    constexpr int ASZ = 64 * AP;        // 66560
    constexpr int WSZ = 512 * 32 * 2;   // 32 KB per W buffer
    extern __shared__ unsigned char lds[];   // ASZ + 2*WSZ = 132096
    unsigned char* Wl = lds + ASZ;

    const int tid  = threadIdx.x;
    const int lane = tid & 63;
    const int w    = tid >> 6;          // wave -> channels [w*128, w*128+128)
    const int fr   = lane & 15;
    const int j4   = lane >> 4;
    const size_t m0 = (size_t)blockIdx.x * 64;
    const float* panel = Af + m0 * 512;

    // ---- contiguous A-panel load: instr i covers bytes [i*4096 + tid*16) ----
    f4 av[32];
#pragma unroll
    for (int i = 0; i < 32; ++i)
        av[i] = *(const f4*)((const unsigned char*)panel + i * 4096 + tid * 16);

    // ---- stage W tiles 0,1 ----
    auto stageW = [&](int t) {
        unsigned char* base = Wl + (t & 1) * WSZ;
        const int kt = t * 32;
#pragma unroll
        for (int i = 0; i < 8; ++i) {
            const int f = i * 256 + tid;
            const int l = f ^ ((f >> 3) & 7);
            gload_lds16(Wb + (size_t)(l >> 2) * 512 + kt + (l & 3) * 8,
                        base + f * 16);
        }
    };
    stageW(0);
    stageW(1);

    // ---- cvt + LDS write of the panel (compiler auto-waits per av[i]) ----
#pragma unroll
    for (int i = 0; i < 32; ++i) {
        const int idx = i * 1024 + tid * 4;     // fp32 index in panel
        const int row = idx >> 9;
        const int k   = idx & 511;
        u32x2 p;
        p[0] = pk2(av[i][0], av[i][1]);
        p[1] = pk2(av[i][2], av[i][3]);
        *(u32x2*)(lds + row * AP + k * 2) = p;
    }
    __syncthreads();   // drains everything (incl. W(0),W(1)) — loop ledger starts at 0

    f4 acc[4][8];
#pragma unroll
    for (int i = 0; i < 4; ++i)
#pragma unroll
        for (int j = 0; j < 8; ++j) acc[i][j] = (f4)(0.0f);

    // ---- K loop: W dbuf, counted vmcnt ----
    for (int t = 0; t < 16; ++t) {
        if (t < 15) asm volatile("s_waitcnt vmcnt(8)" ::: "memory");
        else        asm volatile("s_waitcnt vmcnt(0)" ::: "memory");
        __builtin_amdgcn_s_barrier();
        __builtin_amdgcn_sched_barrier(0);

        unsigned char* wbase = Wl + (t & 1) * WSZ;
        s16x8 wf[8], af[4];
#pragma unroll
        for (int ct = 0; ct < 8; ++ct) {
            const int c = w * 128 + ct * 16 + fr;
            const int L = (c << 2) | j4;
            const int P = L ^ ((L >> 3) & 7);
            wf[ct] = *(const s16x8*)(wbase + (P << 4));
        }
#pragma unroll
        for (int pt = 0; pt < 4; ++pt)
            af[pt] = *(const s16x8*)(lds + (pt * 16 + fr) * AP + t * 64 + j4 * 16);
#pragma unroll
        for (int pt = 0; pt < 4; ++pt)
#pragma unroll
            for (int ct = 0; ct < 8; ++ct)
                acc[pt][ct] = __builtin_amdgcn_mfma_f32_16x16x32_bf16(
                    wf[ct], af[pt], acc[pt][ct], 0, 0, 0);   // D: row=c, col=pix

        __builtin_amdgcn_sched_barrier(0);
        __builtin_amdgcn_s_barrier();
        __builtin_amdgcn_sched_barrier(0);
        if (t + 2 < 16) stageW(t + 2);
    }

    // ---- epilogue: 4 consecutive d per lane -> b64 stores, head-major ----
#pragma unroll
    for (int ct = 0; ct < 8; ++ct) {
        const int c0 = w * 128 + ct * 16 + j4 * 4;
        const f4 b4 = *(const f4*)(bias + c0);
        const int h = c0 >> 5;
        const int d = c0 & 31;
#pragma unroll
        for (int pt = 0; pt < 4; ++pt) {
            const size_t pix = m0 + pt * 16 + fr;
            const f4 v = acc[pt][ct];
            u32x2 p;
            p[0] = pk2((v[0] + b4[0]) * scale, (v[1] + b4[1]) * scale);
            p[1] = pk2((v[2] + b4[2]) * scale, (v[3] + b4[3]) * scale);
            *(u32x2*)(Out + ((size_t)h * NPIX + pix) * 32 + d) = p;
        }
    }
}

// Output GEMM: OUT[pix][c] (fp32) = sum_k X[pix][k] * Wo[c][k] + bias[c],
// X in head-major bf16: K-tile t == head t == contiguous 4KB block -> pure
// gload_lds for both operands, 72 KB LDS, 2 blocks/CU. Standard roles.
__global__ __launch_bounds__(256, 2) void gemm_out(const unsigned short* __restrict__ Xb,
                                                   const unsigned short* __restrict__ Wb,
                                                   const float* __restrict__ bias,
                                                   float* __restrict__ Out) {
    constexpr int XSZ = 4096, WSZ = 32768;
    extern __shared__ unsigned char lds[];      // 2*XSZ + 2*WSZ = 73728
    unsigned char* Wl = lds + 2 * XSZ;

    const int tid  = threadIdx.x;
    const int lane = tid & 63;
    const int w    = tid >> 6;
    const int fr   = lane & 15;
    const int j4   = lane >> 4;
    const size_t m0 = (size_t)blockIdx.x * 64;

    auto stageX = [&](int t) {
        const int f = tid;
        const int l = f ^ ((f >> 3) & 7);
        gload_lds16(Xb + ((size_t)t * NPIX + m0 + (l >> 2)) * 32 + (l & 3) * 8,
                    lds + (t & 1) * XSZ + f * 16);
    };
    auto stageW = [&](int t) {
        unsigned char* base = Wl + (t & 1) * WSZ;
        const int kt = t * 32;
#pragma unroll
        for (int i = 0; i < 8; ++i) {
            const int f = i * 256 + tid;
            const int l = f ^ ((f >> 3) & 7);
            gload_lds16(Wb + (size_t)(l >> 2) * 512 + kt + (l & 3) * 8,
                        base + f * 16);
        }
    };

    stageX(0); stageW(0);
    stageX(1); stageW(1);
    __syncthreads();   // drain; ledger starts at 0

    f4 acc[4][8];
#pragma unroll
    for (int i = 0; i < 4; ++i)
#pragma unroll
        for (int j = 0; j < 8; ++j) acc[i][j] = (f4)(0.0f);

    for (int t = 0; t < 16; ++t) {
        if (t < 15) asm volatile("s_waitcnt vmcnt(9)" ::: "memory");
        else        asm volatile("s_waitcnt vmcnt(0)" ::: "memory");
        __builtin_amdgcn_s_barrier();
        __builtin_amdgcn_sched_barrier(0);

        unsigned char* xbase = lds + (t & 1) * XSZ;
        unsigned char* wbase = Wl + (t & 1) * WSZ;
        s16x8 af[4], wf[8];
#pragma unroll
        for (int pt = 0; pt < 4; ++pt) {
            const int L = ((pt * 16 + fr) << 2) | j4;
            const int P = L ^ ((L >> 3) & 7);
            af[pt] = *(const s16x8*)(xbase + (P << 4));
        }
#pragma unroll
        for (int ct = 0; ct < 8; ++ct) {
            const int c = w * 128 + ct * 16 + fr;
            const int L = (c << 2) | j4;
            const int P = L ^ ((L >> 3) & 7);
            wf[ct] = *(const s16x8*)(wbase + (P << 4));
        }
#pragma unroll
        for (int pt = 0; pt < 4; ++pt)
#pragma unroll
            for (int ct = 0; ct < 8; ++ct)
                acc[pt][ct] = __builtin_amdgcn_mfma_f32_16x16x32_bf16(
                    af[pt], wf[ct], acc[pt][ct], 0, 0, 0);   // D: row=pix, col=c

        __builtin_amdgcn_sched_barrier(0);
        __builtin_amdgcn_s_barrier();
        __builtin_amdgcn_sched_barrier(0);
        if (t + 2 < 16) { stageX(t + 2); stageW(t + 2); }
    }

#pragma unroll
    for (int ct = 0; ct < 8; ++ct) {
        const int c = w * 128 + ct * 16 + fr;
        const float bv = bias[c];
#pragma unroll
        for (int pt = 0; pt < 4; ++pt) {
            const size_t pix = m0 + pt * 16 + j4 * 4;
#pragma unroll
            for (int r = 0; r < 4; ++r)
                Out[(pix + r) * 512 + c] = acc[pt][ct][r] + bv;
        }
    }
}

// LDS-tiled NAT (R8 structure; head-major layout -> contiguous halo rows).
__global__ __launch_bounds__(256, 4) void natt(const unsigned short* __restrict__ qh,
                                               const unsigned short* __restrict__ kh,
                                               const unsigned short* __restrict__ vh,
                                               const float* __restrict__ rpb,
                                               unsigned short* __restrict__ xout) {
    constexpr int LDK = 40;
    __shared__ unsigned short KV[484][LDK];
    __shared__ float Rs[169];

    const int tid = threadIdx.x;
    const int h   = blockIdx.z & 15;
    const int b   = blockIdx.z >> 4;
    const int x0  = blockIdx.x * 16;
    const int y0  = blockIdx.y * 16;
    const int ux0 = min(max(x0 - 3, 0), 106);
    const int uy0 = min(max(y0 - 3, 0), 106);
    const int tx  = tid & 15;
    const int ty  = tid >> 4;
    const int x   = x0 + tx;
    const int y   = y0 + ty;

    if (tid < 169) Rs[tid] = rpb[h * 169 + tid];

    const size_t hb = (size_t)h * NPIX + (size_t)b * 16384;  // head-major base

#pragma unroll 2
    for (int kk = tid; kk < 484; kk += 256) {
        const int ky = uy0 + kk / 22;
        const int kx = ux0 + kk % 22;
        const unsigned short* src = kh + (hb + ky * 128 + kx) * 32;
#pragma unroll
        for (int j = 0; j < 4; ++j)
            *(u16x8*)&KV[kk][j * 8] = *(const u16x8*)(src + j * 8);
    }

    const size_t pix = hb + y * 128 + x;
    const unsigned short* qp = qh + pix * 32;
    f2 qv[16];
#pragma unroll
    for (int j = 0; j < 4; ++j) {
        u16x8 v = *(const u16x8*)(qp + j * 8);
#pragma unroll
        for (int e = 0; e < 4; ++e)
            qv[j * 4 + e] = (f2){bf2f(v[2 * e]), bf2f(v[2 * e + 1])};
    }

    const int myy = min(max(y - 3, 0), 121) - uy0;
    const int myx = min(max(x - 3, 0), 121) - ux0;
    const int pbY = (y < 3) ? (6 - y) : ((y >= 125) ? (127 - y) : 3);
    const int pbX = (x < 3) ? (6 - x) : ((x >= 125) ? (127 - x) : 3);

    __syncthreads();

    float logit[49];
#pragma unroll
    for (int a = 0; a < 7; ++a) {
        const int rowk = (myy + a) * 22 + myx;
#pragma unroll
        for (int c = 0; c < 7; ++c) {
            const u32x4* kp = (const u32x4*)&KV[rowk + c][0];
            f2 sA = {0.f, 0.f}, sB = {0.f, 0.f};
#pragma unroll
            for (int j = 0; j < 4; ++j) {
                const u32x4 wv = kp[j];
                sA += qv[4 * j + 0] * (f2){blo(wv[0]), bhi(wv[0])};
                sB += qv[4 * j + 1] * (f2){blo(wv[1]), bhi(wv[1])};
                sA += qv[4 * j + 2] * (f2){blo(wv[2]), bhi(wv[2])};
                sB += qv[4 * j + 3] * (f2){blo(wv[3]), bhi(wv[3])};
            }
            logit[a * 7 + c] = (sA[0] + sA[1]) + (sB[0] + sB[1])
                             + Rs[(pbY + a) * 13 + pbX + c];
        }
    }

    float m = logit[0];
#pragma unroll
    for (int i = 1; i < 49; ++i) m = fmaxf(m, logit[i]);
    float sum = 0.f;
#pragma unroll
    for (int i = 0; i < 49; ++i) {
        float p = exp2f((logit[i] - m) * 1.4426950408889634f);
        logit[i] = p;
        sum += p;
    }
    const float rinv = 1.f / sum;
#pragma unroll
    for (int i = 0; i < 49; ++i) logit[i] *= rinv;

    __syncthreads();

#pragma unroll 2
    for (int kk = tid; kk < 484; kk += 256) {
        const int ky = uy0 + kk / 22;
        const int kx = ux0 + kk % 22;
        const unsigned short* src = vh + (hb + ky * 128 + kx) * 32;
#pragma unroll
        for (int j = 0; j < 4; ++j)
            *(u16x8*)&KV[kk][j * 8] = *(const u16x8*)(src + j * 8);
    }
    __syncthreads();

    f2 acc2[16];
#pragma unroll
    for (int d = 0; d < 16; ++d) acc2[d] = (f2){0.f, 0.f};
#pragma unroll
    for (int a = 0; a < 7; ++a) {
        const int rowk = (myy + a) * 22 + myx;
#pragma unroll
        for (int c = 0; c < 7; ++c) {
            const u32x4* vp = (const u32x4*)&KV[rowk + c][0];
            const float wgt = logit[a * 7 + c];
            const f2 w2 = {wgt, wgt};
#pragma unroll
            for (int j = 0; j < 4; ++j) {
                const u32x4 wv = vp[j];
                acc2[4 * j + 0] += w2 * (f2){blo(wv[0]), bhi(wv[0])};
                acc2[4 * j + 1] += w2 * (f2){blo(wv[1]), bhi(wv[1])};
                acc2[4 * j + 2] += w2 * (f2){blo(wv[2]), bhi(wv[2])};
                acc2[4 * j + 3] += w2 * (f2){blo(wv[3]), bhi(wv[3])};
            }
        }
    }

    unsigned short* op = xout + pix * 32;
#pragma unroll
    for (int j = 0; j < 4; ++j) {
        unsigned short t[8];
#pragma unroll
        for (int e = 0; e < 4; ++e) {
            t[2 * e]     = f2bf(acc2[j * 4 + e][0]);
            t[2 * e + 1] = f2bf(acc2[j * 4 + e][1]);
        }
        *(u16x8*)(op + j * 8) = *(u16x8*)t;
    }
}

extern "C" void kernel_launch(void* const* d_in, const int* in_sizes, int n_in,
                              void* d_out, int out_size, void* d_ws, size_t ws_size,
                              hipStream_t stream) {
    const float* q   = (const float*)d_in[0];
    const float* k   = (const float*)d_in[1];
    const float* v   = (const float*)d_in[2];
    const float* wq  = (const float*)d_in[3];
    const float* bq  = (const float*)d_in[4];
    const float* wk  = (const float*)d_in[5];
    const float* bk  = (const float*)d_in[6];
    const float* wv  = (const float*)d_in[7];
    const float* bv  = (const float*)d_in[8];
    const float* rpb = (const float*)d_in[9];
    const float* wo  = (const float*)d_in[10];
    const float* bo  = (const float*)d_in[11];

    const long P = NPIX;  // 32768 pixels
    unsigned short* qh = (unsigned short*)d_ws;
    unsigned short* kh = qh + P * 512;
    unsigned short* vh = kh + P * 512;
    unsigned short* xb = vh + P * 512;
    unsigned short* Wb = xb + P * 512;   // 4 x 512 x 512 bf16 (2 MB)

    const float scale = 0.17677669529663687f;  // 32^-0.5
    const size_t smemP = 64 * 1040 + 2 * 512 * 32 * 2;  // 132096
    const size_t smemO = 2 * 4096 + 2 * 32768;          // 73728

    cvt_w4<<<512, 256, 0, stream>>>(wq, wk, wv, wo, Wb);

    gemm_proj<<<512, 256, smemP, stream>>>(q, Wb,          bq, qh, scale);
    gemm_proj<<<512, 256, smemP, stream>>>(k, Wb + 262144, bk, kh, 1.0f);
    gemm_proj<<<512, 256, smemP, stream>>>(v, Wb + 524288, bv, vh, 1.0f);

    natt<<<dim3(8, 8, 32), 256, 0, stream>>>(qh, kh, vh, rpb, xb);

    gemm_out<<<512, 256, smemO, stream>>>(xb, Wb + 786432, bo, (float*)d_out);
}

// Round 11
// 221.449 us; speedup vs baseline: 1.1963x; 1.1963x over previous
//
#include <hip/hip_runtime.h>
#include <hip/hip_bf16.h>

typedef __attribute__((ext_vector_type(8))) _Float16       h8;
typedef __attribute__((ext_vector_type(2))) _Float16       h2;
typedef __attribute__((ext_vector_type(8))) unsigned short u16x8;
typedef __attribute__((ext_vector_type(4))) float          f4;
typedef __attribute__((ext_vector_type(4))) unsigned int   u32x4;
typedef __attribute__((ext_vector_type(2))) unsigned int   u32x2;

__device__ __forceinline__ h2 bch2(unsigned int w) { return __builtin_bit_cast(h2, w); }
// cvt_pkrtz returns __fp16-based vec2; bit_cast its own type (round-10 fix)
__device__ __forceinline__ unsigned int pkrtz(float a, float b) {
    auto r = __builtin_amdgcn_cvt_pkrtz(a, b);
    return __builtin_bit_cast(unsigned int, r);
}
__device__ __forceinline__ void gload_lds16(const void* g, void* l) {
    __builtin_amdgcn_global_load_lds(
        (const __attribute__((address_space(1))) unsigned int*)g,
        (__attribute__((address_space(3))) unsigned int*)l, 16, 0, 0);
}

// Convert the 4 weight matrices (each 512x512 fp32) to f16, concatenated.
__global__ __launch_bounds__(256) void cvt_w4(const float* __restrict__ a,
                                              const float* __restrict__ b,
                                              const float* __restrict__ c,
                                              const float* __restrict__ d,
                                              unsigned short* __restrict__ o) {
    const int i   = (blockIdx.x * 256 + threadIdx.x) * 8;
    const int seg = i >> 18;
    const int off = i & 262143;
    const float* s = (seg == 0) ? a : (seg == 1) ? b : (seg == 2) ? c : d;
    f4 x0 = *(const f4*)(s + off);
    f4 x1 = *(const f4*)(s + off + 4);
    u32x4 t;
    t[0] = pkrtz(x0[0], x0[1]);
    t[1] = pkrtz(x0[2], x0[3]);
    t[2] = pkrtz(x1[0], x1[1]);
    t[3] = pkrtz(x1[2], x1[3]);
    *(u32x4*)(o + i) = t;
}

// R8 gemm_fn body (best measured GEMM), f16 MFMA edition.
// Full-N blocks, double-buffered dynamic LDS, BK=32, counted vmcnt with
// vmcnt(0) tail, both-sides XOR swizzle.
template <bool AF32, bool OF32>
__device__ __forceinline__ void gemm_body(const void* __restrict__ Ap,
                                          const unsigned short* __restrict__ Wb,
                                          const float* __restrict__ bias,
                                          void* __restrict__ Outp,
                                          float scale,
                                          unsigned char* lds) {
    constexpr int KD = 512, BK = 32, NT = KD / BK;            // 16 K-tiles
    constexpr int ASZ = AF32 ? 64 * BK * 4 : 64 * BK * 2;     // 8 KB / 4 KB
    constexpr int WSZ = 512 * BK * 2;                          // 32 KB
    constexpr int STRIDE = ASZ + WSZ;

    const int tid  = threadIdx.x;
    const int lane = tid & 63;
    const int w    = tid >> 6;            // wave -> cols [w*128, w*128+128)
    const size_t m0 = (size_t)blockIdx.x * 64;

    const float*          Af = (const float*)Ap;
    const unsigned short* Ab = (const unsigned short*)Ap;

    const int fr = lane & 15;             // frag row (A) / col (B/D)
    const int j4 = lane >> 4;             // k-slot 0..3

    f4 acc[4][8];
#pragma unroll
    for (int i = 0; i < 4; ++i)
#pragma unroll
        for (int j = 0; j < 8; ++j) acc[i][j] = (f4)(0.0f);

    auto stage = [&](int t, int buf) {
        const int kt = t * BK;
        unsigned char* base = lds + buf * STRIDE;
        if constexpr (AF32) {
#pragma unroll
            for (int i = 0; i < 2; ++i) {
                const int f = i * 256 + tid;
                const int row = f >> 3, p = f & 7;
                const int s = p ^ (row & 7);
                gload_lds16(Af + (m0 + row) * KD + kt + s * 4, base + f * 16);
            }
        } else {
            const int f = tid;
            const int l = f ^ ((f >> 3) & 7);
            gload_lds16(Ab + (m0 + (l >> 2)) * KD + kt + (l & 3) * 8, base + f * 16);
        }
#pragma unroll
        for (int i = 0; i < 8; ++i) {
            const int f = i * 256 + tid;
            const int l = f ^ ((f >> 3) & 7);
            gload_lds16(Wb + (size_t)(l >> 2) * KD + kt + (l & 3) * 8,
                        base + ASZ + f * 16);
        }
    };

    stage(0, 0);
    stage(1, 1);

    for (int t = 0; t < NT; ++t) {
        const int buf = t & 1;
        unsigned char* base = lds + buf * STRIDE;
        if (t + 1 < NT) {
            if constexpr (AF32) asm volatile("s_waitcnt vmcnt(10)" ::: "memory");
            else                asm volatile("s_waitcnt vmcnt(9)"  ::: "memory");
        } else {
            asm volatile("s_waitcnt vmcnt(0)" ::: "memory");
        }
        __builtin_amdgcn_s_barrier();
        __builtin_amdgcn_sched_barrier(0);

        h8 af[4];
#pragma unroll
        for (int mi = 0; mi < 4; ++mi) {
            const int row = mi * 16 + fr;
            if constexpr (AF32) {
                const int r7 = row & 7;
                const int s0 = j4 * 2;
                f4 x0 = *(const f4*)(base + row * 128 + ((s0 ^ r7) << 4));
                f4 x1 = *(const f4*)(base + row * 128 + (((s0 + 1) ^ r7) << 4));
                u32x4 t4;
                t4[0] = pkrtz(x0[0], x0[1]);
                t4[1] = pkrtz(x0[2], x0[3]);
                t4[2] = pkrtz(x1[0], x1[1]);
                t4[3] = pkrtz(x1[2], x1[3]);
                af[mi] = __builtin_bit_cast(h8, t4);
            } else {
                const int L = (row << 2) | j4;
                const int P = L ^ ((L >> 3) & 7);
                af[mi] = *(const h8*)(base + (P << 4));
            }
        }
#pragma unroll
        for (int ni = 0; ni < 8; ++ni) {
            const int nrow = w * 128 + ni * 16 + fr;
            const int L = (nrow << 2) | j4;
            const int P = L ^ ((L >> 3) & 7);
            const h8 bf = *(const h8*)(base + ASZ + (P << 4));
#pragma unroll
            for (int mi = 0; mi < 4; ++mi)
                acc[mi][ni] = __builtin_amdgcn_mfma_f32_16x16x32_f16(
                    af[mi], bf, acc[mi][ni], 0, 0, 0);
        }

        __builtin_amdgcn_sched_barrier(0);
        __builtin_amdgcn_s_barrier();
        __builtin_amdgcn_sched_barrier(0);
        if (t + 2 < NT) stage(t + 2, buf);
    }

    const int rq = (lane >> 4) << 2;
#pragma unroll
    for (int ni = 0; ni < 8; ++ni) {
        const int   col = w * 128 + ni * 16 + fr;
        const float bv  = bias[col];
#pragma unroll
        for (int mi = 0; mi < 4; ++mi) {
            const size_t rbase = m0 + mi * 16 + rq;
#pragma unroll
            for (int r = 0; r < 4; ++r) {
                const float val = (acc[mi][ni][r] + bv) * scale;
                if constexpr (OF32) {
                    ((float*)Outp)[(rbase + r) * KD + col] = val;
                } else {
                    const _Float16 hv = (_Float16)val;
                    ((unsigned short*)Outp)[(rbase + r) * KD + col] =
                        __builtin_bit_cast(unsigned short, hv);
                }
            }
        }
    }
}

// 3 projections in one launch: blockIdx.y selects (input, weight, bias, out).
__global__ __launch_bounds__(256, 2) void gemm_proj3(const float* __restrict__ q,
                                                     const float* __restrict__ k,
                                                     const float* __restrict__ v,
                                                     const unsigned short* __restrict__ Wb,
                                                     const float* __restrict__ bq,
                                                     const float* __restrict__ bk,
                                                     const float* __restrict__ bv,
                                                     unsigned short* __restrict__ qh,
                                                     unsigned short* __restrict__ kh,
                                                     unsigned short* __restrict__ vh,
                                                     float scale) {
    extern __shared__ unsigned char lds[];
    const int by = blockIdx.y;
    const float*          A  = (by == 0) ? q  : (by == 1) ? k  : v;
    const float*          bi = (by == 0) ? bq : (by == 1) ? bk : bv;
    unsigned short*       O  = (by == 0) ? qh : (by == 1) ? kh : vh;
    gemm_body<true, false>(A, Wb + (size_t)by * 262144, bi, O,
                           (by == 0) ? scale : 1.0f, lds);
}

__global__ __launch_bounds__(256, 2) void gemm_outk(const unsigned short* __restrict__ Xb,
                                                    const unsigned short* __restrict__ Wb,
                                                    const float* __restrict__ bias,
                                                    float* __restrict__ Out) {
    extern __shared__ unsigned char lds[];
    gemm_body<false, true>(Xb, Wb, bias, Out, 1.0f, lds);
}

// LDS-tiled NAT, f16 edition: QK via v_dot2_f32_f16 (no unpack), PV via
// fma_mix pattern (f16 ext + fma fuse). R8 pixel-major layout.
__global__ __launch_bounds__(256, 4) void natt(const unsigned short* __restrict__ qh,
                                               const unsigned short* __restrict__ kh,
                                               const unsigned short* __restrict__ vh,
                                               const float* __restrict__ rpb,
                                               unsigned short* __restrict__ xout) {
    constexpr int LDK = 40;
    __shared__ unsigned short KV[484][LDK];
    __shared__ float Rs[169];

    const int tid = threadIdx.x;
    const int h   = blockIdx.z & 15;
    const int b   = blockIdx.z >> 4;
    const int x0  = blockIdx.x * 16;
    const int y0  = blockIdx.y * 16;
    const int ux0 = min(max(x0 - 3, 0), 106);
    const int uy0 = min(max(y0 - 3, 0), 106);
    const int tx  = tid & 15;
    const int ty  = tid >> 4;
    const int x   = x0 + tx;
    const int y   = y0 + ty;

    if (tid < 169) Rs[tid] = rpb[h * 169 + tid];

    const long imgbase = (long)b * 128 * 128;

#pragma unroll 2
    for (int kk = tid; kk < 484; kk += 256) {
        const int ky = uy0 + kk / 22;
        const int kx = ux0 + kk % 22;
        const unsigned short* src = kh + (imgbase + ky * 128 + kx) * 512 + h * 32;
#pragma unroll
        for (int j = 0; j < 4; ++j)
            *(u16x8*)&KV[kk][j * 8] = *(const u16x8*)(src + j * 8);
    }

    const long pix = imgbase + y * 128 + x;
    const unsigned short* qp = qh + pix * 512 + h * 32;
    h2 qv[16];
    {
        const u32x4* q32 = (const u32x4*)qp;
#pragma unroll
        for (int j = 0; j < 4; ++j) {
            const u32x4 wv = q32[j];
#pragma unroll
            for (int e = 0; e < 4; ++e) qv[j * 4 + e] = bch2(wv[e]);
        }
    }

    const int myy = min(max(y - 3, 0), 121) - uy0;
    const int myx = min(max(x - 3, 0), 121) - ux0;
    const int pbY = (y < 3) ? (6 - y) : ((y >= 125) ? (127 - y) : 3);
    const int pbX = (x < 3) ? (6 - x) : ((x >= 125) ? (127 - x) : 3);

    __syncthreads();

    float logit[49];
#pragma unroll
    for (int a = 0; a < 7; ++a) {
        const int rowk = (myy + a) * 22 + myx;
#pragma unroll
        for (int c = 0; c < 7; ++c) {
            const u32x4* kp = (const u32x4*)&KV[rowk + c][0];
            float s0 = 0.f, s1 = 0.f;
#pragma unroll
            for (int j = 0; j < 4; ++j) {
                const u32x4 wv = kp[j];
                s0 = __builtin_amdgcn_fdot2(qv[4 * j + 0], bch2(wv[0]), s0, false);
                s1 = __builtin_amdgcn_fdot2(qv[4 * j + 1], bch2(wv[1]), s1, false);
                s0 = __builtin_amdgcn_fdot2(qv[4 * j + 2], bch2(wv[2]), s0, false);
                s1 = __builtin_amdgcn_fdot2(qv[4 * j + 3], bch2(wv[3]), s1, false);
            }
            logit[a * 7 + c] = s0 + s1 + Rs[(pbY + a) * 13 + pbX + c];
        }
    }

    float m = logit[0];
#pragma unroll
    for (int i = 1; i < 49; ++i) m = fmaxf(m, logit[i]);
    float sum = 0.f;
#pragma unroll
    for (int i = 0; i < 49; ++i) {
        float p = exp2f((logit[i] - m) * 1.4426950408889634f);
        logit[i] = p;
        sum += p;
    }
    const float rinv = 1.f / sum;
#pragma unroll
    for (int i = 0; i < 49; ++i) logit[i] *= rinv;

    __syncthreads();

#pragma unroll 2
    for (int kk = tid; kk < 484; kk += 256) {
        const int ky = uy0 + kk / 22;
        const int kx = ux0 + kk % 22;
        const unsigned short* src = vh + (imgbase + ky * 128 + kx) * 512 + h * 32;
#pragma unroll
        for (int j = 0; j < 4; ++j)
            *(u16x8*)&KV[kk][j * 8] = *(const u16x8*)(src + j * 8);
    }
    __syncthreads();

    float acc[32];
#pragma unroll
    for (int d = 0; d < 32; ++d) acc[d] = 0.f;
#pragma unroll
    for (int a = 0; a < 7; ++a) {
        const int rowk = (myy + a) * 22 + myx;
#pragma unroll
        for (int c = 0; c < 7; ++c) {
            const u32x4* vp = (const u32x4*)&KV[rowk + c][0];
            const float wgt = logit[a * 7 + c];
#pragma unroll
            for (int j = 0; j < 4; ++j) {
                const u32x4 wv = vp[j];
#pragma unroll
                for (int e = 0; e < 4; ++e) {
                    const h2 hv = bch2(wv[e]);
                    acc[8 * j + 2 * e]     = fmaf((float)hv[0], wgt, acc[8 * j + 2 * e]);
                    acc[8 * j + 2 * e + 1] = fmaf((float)hv[1], wgt, acc[8 * j + 2 * e + 1]);
                }
            }
        }
    }

    unsigned short* op = xout + pix * 512 + h * 32;
#pragma unroll
    for (int j = 0; j < 4; ++j) {
        u32x2 p;
        p[0] = pkrtz(acc[8 * j + 0], acc[8 * j + 1]);
        p[1] = pkrtz(acc[8 * j + 2], acc[8 * j + 3]);
        u32x2 p2;
        p2[0] = pkrtz(acc[8 * j + 4], acc[8 * j + 5]);
        p2[1] = pkrtz(acc[8 * j + 6], acc[8 * j + 7]);
        *(u32x2*)(op + j * 8)     = p;
        *(u32x2*)(op + j * 8 + 4) = p2;
    }
}

extern "C" void kernel_launch(void* const* d_in, const int* in_sizes, int n_in,
                              void* d_out, int out_size, void* d_ws, size_t ws_size,
                              hipStream_t stream) {
    const float* q   = (const float*)d_in[0];
    const float* k   = (const float*)d_in[1];
    const float* v   = (const float*)d_in[2];
    const float* wq  = (const float*)d_in[3];
    const float* bq  = (const float*)d_in[4];
    const float* wk  = (const float*)d_in[5];
    const float* bk  = (const float*)d_in[6];
    const float* wv  = (const float*)d_in[7];
    const float* bv  = (const float*)d_in[8];
    const float* rpb = (const float*)d_in[9];
    const float* wo  = (const float*)d_in[10];
    const float* bo  = (const float*)d_in[11];

    const long P = 2l * 128 * 128;  // 32768 pixels
    unsigned short* qh = (unsigned short*)d_ws;
    unsigned short* kh = qh + P * 512;
    unsigned short* vh = kh + P * 512;
    unsigned short* xb = vh + P * 512;
    unsigned short* Wb = xb + P * 512;   // 4 x 512 x 512 f16 (2 MB)

    const float scale = 0.17677669529663687f;  // 32^-0.5
    const size_t smemF = 2 * (64 * 32 * 4 + 512 * 32 * 2);  // 81920
    const size_t smemB = 2 * (64 * 32 * 2 + 512 * 32 * 2);  // 73728

    cvt_w4<<<512, 256, 0, stream>>>(wq, wk, wv, wo, Wb);

    gemm_proj3<<<dim3(512, 3, 1), 256, smemF, stream>>>(
        q, k, v, Wb, bq, bk, bv, qh, kh, vh, scale);

    natt<<<dim3(8, 8, 32), 256, 0, stream>>>(qh, kh, vh, rpb, xb);

    gemm_outk<<<512, 256, smemB, stream>>>(xb, Wb + 786432, bo, (float*)d_out);
}